// Round 16
// baseline (61.853 us; speedup 1.0000x reference)
//
#include <hip/hip_runtime.h>
#include <math.h>

#define N_ATOMS 4096
#define SPECIES 100
#define FEA 64
#define M_NBR 12

typedef unsigned short u16;
typedef __attribute__((ext_vector_type(8))) _Float16 f16x8;
typedef __attribute__((ext_vector_type(4))) float f32x4;

constexpr float LN_EPS = 1e-5f;
constexpr float GAUSS_COEFF = -31.0078125f; // -0.5/(8/63)^2
constexpr float D2_INF = 3.4e38f;

__device__ __forceinline__ float sigmoidf_(float x){
    return __fdividef(1.0f, 1.0f + __expf(-x));
}
__device__ __forceinline__ float softplusf_(float x){
    return fmaxf(x, 0.0f) + __logf(1.0f + __expf(-fabsf(x)));
}
__device__ __forceinline__ u16 f16bits(_Float16 h){ return *(u16*)&h; }

// ---------------- setup: wpk pack + fracs transpose + embedding ----------------
// wpk: 6 mats (S1,N1,G1,S2,N2,G2) of 16KB fp16; within a mat:
// dest[((ch*8+nt)*64+lane)*8 + i] = W[k=ch*32+(lane>>4)*8+i][n=nt*16+(lane&15)]
__global__ __launch_bounds__(256) void k_setup(const float* __restrict__ fracs,
        const float* __restrict__ w1, const float* __restrict__ w2,
        const float* __restrict__ logits, const float* __restrict__ emb_w,
        const float* __restrict__ emb_b,
        float* __restrict__ fx, float* __restrict__ fy, float* __restrict__ fz,
        u16* __restrict__ wpk, float* __restrict__ atom0, u16* __restrict__ a0f){
    __shared__ float sE[4][SPECIES];
    int b = blockIdx.x, t = threadIdx.x;
    if (b < 192){
        int gid = b * 256 + t;
        int layer = gid / 24576;
        int e = gid % 24576;
        int k = e >> 7, n = e & 127;
        float x = (layer ? w2 : w1)[e];
        int mat = layer * 3 + (k >> 6);
        int kk = k & 63;
        int ch = kk >> 5, lg2 = (kk >> 3) & 3, i = kk & 7;
        int nt = n >> 4, lr2 = n & 15;
        wpk[mat * 8192 + ((ch * 8 + nt) * 64 + (lg2 * 16 + lr2)) * 8 + i] = f16bits((_Float16)x);
    } else if (b < 208){
        int j = (b - 192) * 256 + t;
        fx[j] = fracs[j*3+0];
        fy[j] = fracs[j*3+1];
        fz[j] = fracs[j*3+2];
    } else {
        int grp = t >> 6, f = t & 63;
        int a = (b - 208) * 4 + grp;
        const float* lg = logits + (long)a * SPECIES;
        float l0 = lg[f];
        float l1 = (f + 64 < SPECIES) ? lg[f + 64] : -1e30f;
        float mx = fmaxf(l0, l1);
        #pragma unroll
        for (int off = 32; off; off >>= 1) mx = fmaxf(mx, __shfl_xor(mx, off));
        float e0 = __expf(l0 - mx);
        float e1 = (f + 64 < SPECIES) ? __expf(l1 - mx) : 0.0f;
        sE[grp][f] = e0;
        if (f + 64 < SPECIES) sE[grp][64 + f] = e1;
        float sm = e0 + e1;
        #pragma unroll
        for (int off = 32; off; off >>= 1) sm += __shfl_xor(sm, off);
        __syncthreads();
        float acc = 0.0f;
        for (int s = 0; s < SPECIES; ++s) acc += sE[grp][s] * emb_w[s * FEA + f];
        float v = acc / sm + emb_b[f];
        atom0[(long)a * FEA + f] = v;
        a0f[a * FEA + f] = f16bits((_Float16)v);
    }
}

// ---------------- top-12: histogram threshold + compaction + parallel rank select ----------------
__global__ __launch_bounds__(256) void k_topk(const float* __restrict__ fx,
        const float* __restrict__ fy, const float* __restrict__ fz,
        const float* __restrict__ lat, int* __restrict__ nbr_idx,
        float* __restrict__ nbr_dist){
    __shared__ int   hist[256];
    __shared__ int   cnt;
    __shared__ float sThr;
    __shared__ float candD[256];
    __shared__ int   candI[256];
    int i = blockIdx.x, tid = threadIdx.x;
    hist[tid] = 0;
    if (tid == 0) cnt = 0;
    __syncthreads();
    float l00=lat[0],l01=lat[1],l02=lat[2];
    float l10=lat[3],l11=lat[4],l12=lat[5];
    float l20=lat[6],l21=lat[7],l22=lat[8];
    float xi = fx[i], yi = fy[i], zi = fz[i];
    float d2r[16];
    #pragma unroll
    for (int k = 0; k < 16; ++k){
        int j = tid + k * 256;
        float dx = xi - fx[j];
        float dy = yi - fy[j];
        float dz = zi - fz[j];
        dx -= rintf(dx); dy -= rintf(dy); dz -= rintf(dz);
        float cx = dx*l00 + dy*l10 + dz*l20;
        float cy = dx*l01 + dy*l11 + dz*l21;
        float cz = dx*l02 + dy*l12 + dz*l22;
        float d2 = cx*cx + cy*cy + cz*cz;
        if (j == i) d2 = D2_INF;
        d2r[k] = d2;
        if (d2 < 4.0f) atomicAdd(&hist[(int)(d2 * 64.0f)], 1);
    }
    __syncthreads();
    if (tid < 64){
        int s0 = hist[4*tid] + hist[4*tid+1] + hist[4*tid+2] + hist[4*tid+3];
        int sc = s0;
        #pragma unroll
        for (int off = 1; off < 64; off <<= 1){
            int o = __shfl_up(sc, off);
            if (tid >= off) sc += o;
        }
        unsigned long long mball = __ballot(sc >= M_NBR);
        if (mball == 0ULL){
            if (tid == 0) sThr = 1e30f;
        } else {
            int gbin = __ffsll(mball) - 1;
            if (tid == gbin){
                int c = sc - s0;
                float th = 4.0f;
                #pragma unroll
                for (int b = 0; b < 4; ++b){
                    c += hist[4*gbin + b];
                    if (c >= M_NBR){ th = (float)(4*gbin + b + 1) * (1.0f/64.0f); break; }
                }
                sThr = th;
            }
        }
    }
    __syncthreads();
    float thr = sThr;
    #pragma unroll
    for (int k = 0; k < 16; ++k){
        if (d2r[k] < thr){
            int p = atomicAdd(&cnt, 1);
            if (p < 256){ candD[p] = d2r[k]; candI[p] = tid + k * 256; }
        }
    }
    __syncthreads();
    int n = cnt < 256 ? cnt : 256;
    for (int c = tid; c < n; c += 256){
        float dv = candD[c]; int iv = candI[c];
        int rank = 0;
        for (int s = 0; s < n; ++s){
            float ds_ = candD[s]; int is_ = candI[s];
            rank += (ds_ < dv || (ds_ == dv && is_ < iv)) ? 1 : 0;
        }
        if (rank < M_NBR){
            nbr_idx[i * M_NBR + rank]  = iv;
            nbr_dist[i * M_NBR + rank] = sqrtf(dv);
        }
    }
}

// ---------------- one atom per wave: both layers, zero inter-wave coupling ----------------
// Block = 64 thr (1 wave) = 1 atom. Rows 0-11 of the 16-row M-tile are the atom's
// neighbors (rows 12-15 = lane-group lg3 padding, excluded from sums). Self-GEMM via
// broadcast-A accumulates into the SAME acc as nbr+gauss (every C row = S[atom]).
// Epilogue in-register (shfl); only a 128B LDS buffer redistributes layer-1 output.
__global__ __launch_bounds__(64, 4) void k_atom(
        const float* __restrict__ atom0F, const u16* __restrict__ a0f,
        const int* __restrict__ nbr_idx, const float* __restrict__ nbr_dist,
        const u16* __restrict__ wpk,
        const float* __restrict__ b1, const float* __restrict__ g1, const float* __restrict__ be1,
        const float* __restrict__ b2, const float* __restrict__ g2, const float* __restrict__ be2,
        float* __restrict__ outF)
{
    __shared__ u16   sH[64];   // layer-1 out fp16 (A-frag redistribution)
    __shared__ float sO[64];   // final output staging (coalesced store)

    const int a = blockIdx.x;
    const int l = threadIdx.x;
    const int lg = l >> 4, lr = l & 15;

    // prologue: all independent loads
    const int slot = (lr < 12) ? lr : 11;
    const int nid  = nbr_idx[a * M_NBR + slot];
    const float dist = nbr_dist[a * M_NBR + slot];
    f16x8 nfr[2], saf[2];
    nfr[0] = *(const f16x8*)(a0f + nid * 64 + lg * 8);
    nfr[1] = *(const f16x8*)(a0f + nid * 64 + 32 + lg * 8);
    saf[0] = *(const f16x8*)(a0f + a * 64 + lg * 8);        // broadcast-A (same for all lr)
    saf[1] = *(const f16x8*)(a0f + a * 64 + 32 + lg * 8);
    float resv[4];
    #pragma unroll
    for (int nt = 0; nt < 4; ++nt)
        resv[nt] = atom0F[(long)a * 64 + nt * 16 + lr];

    f16x8 ga[2];
    #pragma unroll
    for (int c = 0; c < 2; ++c)
        #pragma unroll
        for (int i = 0; i < 8; ++i){
            int k = c * 32 + lg * 8 + i;
            float dd = dist - (float)k * (8.0f / 63.0f);
            ga[c][i] = (_Float16)__expf(GAUSS_COEFF * dd * dd);
        }

    #pragma unroll 1
    for (int layer = 0; layer < 2; ++layer){
        const u16* wb = wpk + layer * 3 * 8192;
        const float* bb  = layer ? b2  : b1;
        const float* gg  = layer ? g2  : g1;
        const float* bee = layer ? be2 : be1;

        // fused S+N+G MFMA into one accumulator
        f32x4 acc[8];
        #pragma unroll
        for (int nt = 0; nt < 8; ++nt) acc[nt] = 0.0f;
        #pragma unroll
        for (int c = 0; c < 2; ++c)
            #pragma unroll
            for (int nt = 0; nt < 8; ++nt){
                const f16x8 bS = *(const f16x8*)(wb +          ((c * 8 + nt) * 64 + l) * 8);
                const f16x8 bN = *(const f16x8*)(wb +  8192 + ((c * 8 + nt) * 64 + l) * 8);
                const f16x8 bG = *(const f16x8*)(wb + 16384 + ((c * 8 + nt) * 64 + l) * 8);
                acc[nt] = __builtin_amdgcn_mfma_f32_16x16x32_f16(saf[c], bS, acc[nt], 0, 0, 0);
                acc[nt] = __builtin_amdgcn_mfma_f32_16x16x32_f16(nfr[c], bN, acc[nt], 0, 0, 0);
                acc[nt] = __builtin_amdgcn_mfma_f32_16x16x32_f16(ga[c],  bG, acc[nt], 0, 0, 0);
            }

        // z = acc + bias; LN per row (row = lg*4+rr; cols nt*16+lr)
        float s[4] = {0,0,0,0}, q[4] = {0,0,0,0};
        #pragma unroll
        for (int nt = 0; nt < 8; ++nt){
            float bv = bb[nt * 16 + lr];
            #pragma unroll
            for (int rr = 0; rr < 4; ++rr){
                float v = acc[nt][rr] + bv;
                acc[nt][rr] = v;
                s[rr] += v; q[rr] += v * v;
            }
        }
        #pragma unroll
        for (int rr = 0; rr < 4; ++rr){
            #pragma unroll
            for (int m = 1; m < 16; m <<= 1){
                s[rr] += __shfl_xor(s[rr], m);
                q[rr] += __shfl_xor(q[rr], m);
            }
        }
        // products + per-atom reduction, all in registers
        float nsum[4];
        #pragma unroll
        for (int nt = 0; nt < 4; ++nt){
            float gf = gg[nt * 16 + lr],      bef = bee[nt * 16 + lr];
            float gc = gg[64 + nt * 16 + lr], bec = bee[64 + nt * 16 + lr];
            float part = 0.0f;
            #pragma unroll
            for (int rr = 0; rr < 4; ++rr){
                float mean = s[rr] * (1.0f / 128.0f);
                float var  = q[rr] * (1.0f / 128.0f) - mean * mean;
                float inv  = rsqrtf(var + LN_EPS);
                float zf = (acc[nt][rr]     - mean) * inv * gf + bef;
                float zc = (acc[nt + 4][rr] - mean) * inv * gc + bec;
                part += sigmoidf_(zf) * softplusf_(zc);
            }
            if (lg == 3) part = 0.0f;          // padding rows 12-15
            part += __shfl_xor(part, 16);
            part += __shfl_xor(part, 32);
            nsum[nt] = part;
        }
        #pragma unroll
        for (int nt = 0; nt < 4; ++nt)
            resv[nt] = softplusf_(resv[nt] + nsum[nt]);

        if (layer == 0){
            if (lg == 0){
                #pragma unroll
                for (int nt = 0; nt < 4; ++nt)
                    sH[nt * 16 + lr] = f16bits((_Float16)resv[nt]);
            }
            __syncthreads();
            saf[0] = *(const f16x8*)(&sH[lg * 8]);
            saf[1] = *(const f16x8*)(&sH[32 + lg * 8]);
        } else {
            if (lg == 0){
                #pragma unroll
                for (int nt = 0; nt < 4; ++nt)
                    sO[nt * 16 + lr] = resv[nt];
            }
            __syncthreads();
            outF[(long)a * 64 + l] = sO[l];
        }
    }
}

// ---------------- pooling: deterministic two-stage tree ----------------
__global__ __launch_bounds__(256) void k_partial(const float* __restrict__ atom,
        const float* __restrict__ occ, float* __restrict__ partials){
    int b = blockIdx.x, tid = threadIdx.x;
    int f = tid & 63, sub = tid >> 6;
    __shared__ float sAcc[256];
    float acc = 0.0f;
    for (int it = 0; it < 16; ++it){
        int a = b * 64 + sub + it * 4;
        float p = sigmoidf_(occ[a]);
        acc += atom[(long)a * FEA + f] * p;
    }
    sAcc[tid] = acc;
    __syncthreads();
    if (tid < 64){
        float s = sAcc[f] + sAcc[64 + f] + sAcc[128 + f] + sAcc[192 + f];
        partials[b * 65 + f] = s;
        float po = sigmoidf_(occ[b * 64 + f]);
        #pragma unroll
        for (int off = 32; off; off >>= 1) po += __shfl_down(po, off);
        if (f == 0) partials[b * 65 + 64] = po;
    }
}

__global__ __launch_bounds__(64) void k_final(const float* __restrict__ partials,
        const float* __restrict__ fc_w, const float* __restrict__ fc_b,
        float* __restrict__ out){
    int f = threadIdx.x;
    float num = 0.0f;
    for (int p = 0; p < 64; ++p) num += partials[p * 65 + f];
    float occs = partials[f * 65 + 64];
    #pragma unroll
    for (int off = 32; off; off >>= 1) occs += __shfl_down(occs, off);
    occs = __shfl(occs, 0);
    float gf = num / (occs + 1e-6f);
    float v = gf * fc_w[f];
    #pragma unroll
    for (int off = 32; off; off >>= 1) v += __shfl_down(v, off);
    if (f == 0) out[0] = v + fc_b[0];
}

extern "C" void kernel_launch(void* const* d_in, const int* in_sizes, int n_in,
                              void* d_out, int out_size, void* d_ws, size_t ws_size,
                              hipStream_t stream) {
    const float* lat    = (const float*)d_in[0];
    const float* fracs  = (const float*)d_in[1];
    const float* slog   = (const float*)d_in[2];
    const float* occ    = (const float*)d_in[3];
    const float* emb_w  = (const float*)d_in[4];
    const float* emb_b  = (const float*)d_in[5];
    const float* w1     = (const float*)d_in[6];
    const float* b1     = (const float*)d_in[7];
    const float* g1     = (const float*)d_in[8];
    const float* be1    = (const float*)d_in[9];
    const float* w2     = (const float*)d_in[10];
    const float* b2     = (const float*)d_in[11];
    const float* g2     = (const float*)d_in[12];
    const float* be2    = (const float*)d_in[13];
    const float* fc_w   = (const float*)d_in[14];
    const float* fc_b   = (const float*)d_in[15];
    float* out = (float*)d_out;

    char* ws = (char*)d_ws;
    auto alloc = [&](size_t bytes) -> void* {
        void* p = (void*)ws;
        ws += (bytes + 255) & ~(size_t)255;
        return p;
    };
    int*   nbr_idx  = (int*)  alloc((size_t)N_ATOMS * M_NBR * 4);
    float* nbr_dist = (float*)alloc((size_t)N_ATOMS * M_NBR * 4);
    float* atom0    = (float*)alloc((size_t)N_ATOMS * FEA * 4);
    float* atom1    = (float*)alloc((size_t)N_ATOMS * FEA * 4);
    u16*   a0f      = (u16*)  alloc((size_t)N_ATOMS * FEA * 2);
    u16*   wpk      = (u16*)  alloc((size_t)6 * 8192 * 2);
    float* fxa      = (float*)alloc((size_t)N_ATOMS * 4);
    float* fya      = (float*)alloc((size_t)N_ATOMS * 4);
    float* fza      = (float*)alloc((size_t)N_ATOMS * 4);
    float* partials = (float*)alloc((size_t)64 * 65 * 4);

    k_setup  <<<208 + N_ATOMS / 4, 256, 0, stream>>>(fracs, w1, w2, slog, emb_w, emb_b,
                fxa, fya, fza, wpk, atom0, a0f);
    k_topk   <<<N_ATOMS, 256, 0, stream>>>(fxa, fya, fza, lat, nbr_idx, nbr_dist);
    k_atom   <<<N_ATOMS, 64, 0, stream>>>(atom0, a0f, nbr_idx, nbr_dist,
                wpk, b1, g1, be1, b2, g2, be2, atom1);
    k_partial<<<64, 256, 0, stream>>>(atom1, occ, partials);
    k_final  <<<1, 64, 0, stream>>>(partials, fc_w, fc_b, out);
}

// Round 17
// 58.911 us; speedup vs baseline: 1.0499x; 1.0499x over previous
//
#include <hip/hip_runtime.h>
#include <math.h>

#define N_ATOMS 4096
#define SPECIES 100
#define FEA 64
#define M_NBR 12

typedef unsigned short u16;
typedef __attribute__((ext_vector_type(8))) _Float16 f16x8;
typedef __attribute__((ext_vector_type(4))) float f32x4;

constexpr float LN_EPS = 1e-5f;
constexpr float GAUSS_COEFF = -31.0078125f; // -0.5/(8/63)^2
constexpr float D2_INF = 3.4e38f;

__device__ __forceinline__ float sigmoidf_(float x){
    return __fdividef(1.0f, 1.0f + __expf(-x));
}
__device__ __forceinline__ float softplusf_(float x){
    return fmaxf(x, 0.0f) + __logf(1.0f + __expf(-fabsf(x)));
}
__device__ __forceinline__ u16 f16bits(_Float16 h){ return *(u16*)&h; }

// ---------------- setup: wpk pack + fracs transpose + embedding ----------------
// wpk: 6 mats (S1,N1,G1,S2,N2,G2) of 16KB fp16; within a mat:
// dest[((ch*8+nt)*64+lane)*8 + i] = W[k=ch*32+(lane>>4)*8+i][n=nt*16+(lane&15)]
__global__ __launch_bounds__(256) void k_setup(const float* __restrict__ fracs,
        const float* __restrict__ w1, const float* __restrict__ w2,
        const float* __restrict__ logits, const float* __restrict__ emb_w,
        const float* __restrict__ emb_b,
        float* __restrict__ fx, float* __restrict__ fy, float* __restrict__ fz,
        u16* __restrict__ wpk, float* __restrict__ atom0, u16* __restrict__ a0f){
    __shared__ float sE[4][SPECIES];
    int b = blockIdx.x, t = threadIdx.x;
    if (b < 192){
        int gid = b * 256 + t;
        int layer = gid / 24576;
        int e = gid % 24576;
        int k = e >> 7, n = e & 127;
        float x = (layer ? w2 : w1)[e];
        int mat = layer * 3 + (k >> 6);
        int kk = k & 63;
        int ch = kk >> 5, lg2 = (kk >> 3) & 3, i = kk & 7;
        int nt = n >> 4, lr2 = n & 15;
        wpk[mat * 8192 + ((ch * 8 + nt) * 64 + (lg2 * 16 + lr2)) * 8 + i] = f16bits((_Float16)x);
    } else if (b < 208){
        int j = (b - 192) * 256 + t;
        fx[j] = fracs[j*3+0];
        fy[j] = fracs[j*3+1];
        fz[j] = fracs[j*3+2];
    } else {
        int grp = t >> 6, f = t & 63;
        int a = (b - 208) * 4 + grp;
        const float* lg = logits + (long)a * SPECIES;
        float l0 = lg[f];
        float l1 = (f + 64 < SPECIES) ? lg[f + 64] : -1e30f;
        float mx = fmaxf(l0, l1);
        #pragma unroll
        for (int off = 32; off; off >>= 1) mx = fmaxf(mx, __shfl_xor(mx, off));
        float e0 = __expf(l0 - mx);
        float e1 = (f + 64 < SPECIES) ? __expf(l1 - mx) : 0.0f;
        sE[grp][f] = e0;
        if (f + 64 < SPECIES) sE[grp][64 + f] = e1;
        float sm = e0 + e1;
        #pragma unroll
        for (int off = 32; off; off >>= 1) sm += __shfl_xor(sm, off);
        __syncthreads();
        float acc = 0.0f;
        for (int s = 0; s < SPECIES; ++s) acc += sE[grp][s] * emb_w[s * FEA + f];
        float v = acc / sm + emb_b[f];
        atom0[(long)a * FEA + f] = v;
        a0f[a * FEA + f] = f16bits((_Float16)v);
    }
}

// ---------------- top-12: histogram threshold + compaction + parallel rank select ----------------
__global__ __launch_bounds__(256) void k_topk(const float* __restrict__ fx,
        const float* __restrict__ fy, const float* __restrict__ fz,
        const float* __restrict__ lat, int* __restrict__ nbr_idx,
        float* __restrict__ nbr_dist){
    __shared__ int   hist[256];
    __shared__ int   cnt;
    __shared__ float sThr;
    __shared__ float candD[256];
    __shared__ int   candI[256];
    int i = blockIdx.x, tid = threadIdx.x;
    hist[tid] = 0;
    if (tid == 0) cnt = 0;
    __syncthreads();
    float l00=lat[0],l01=lat[1],l02=lat[2];
    float l10=lat[3],l11=lat[4],l12=lat[5];
    float l20=lat[6],l21=lat[7],l22=lat[8];
    float xi = fx[i], yi = fy[i], zi = fz[i];
    float d2r[16];
    #pragma unroll
    for (int k = 0; k < 16; ++k){
        int j = tid + k * 256;
        float dx = xi - fx[j];
        float dy = yi - fy[j];
        float dz = zi - fz[j];
        dx -= rintf(dx); dy -= rintf(dy); dz -= rintf(dz);
        float cx = dx*l00 + dy*l10 + dz*l20;
        float cy = dx*l01 + dy*l11 + dz*l21;
        float cz = dx*l02 + dy*l12 + dz*l22;
        float d2 = cx*cx + cy*cy + cz*cz;
        if (j == i) d2 = D2_INF;
        d2r[k] = d2;
        if (d2 < 4.0f) atomicAdd(&hist[(int)(d2 * 64.0f)], 1);
    }
    __syncthreads();
    if (tid < 64){
        int s0 = hist[4*tid] + hist[4*tid+1] + hist[4*tid+2] + hist[4*tid+3];
        int sc = s0;
        #pragma unroll
        for (int off = 1; off < 64; off <<= 1){
            int o = __shfl_up(sc, off);
            if (tid >= off) sc += o;
        }
        unsigned long long mball = __ballot(sc >= M_NBR);
        if (mball == 0ULL){
            if (tid == 0) sThr = 1e30f;
        } else {
            int gbin = __ffsll(mball) - 1;
            if (tid == gbin){
                int c = sc - s0;
                float th = 4.0f;
                #pragma unroll
                for (int b = 0; b < 4; ++b){
                    c += hist[4*gbin + b];
                    if (c >= M_NBR){ th = (float)(4*gbin + b + 1) * (1.0f/64.0f); break; }
                }
                sThr = th;
            }
        }
    }
    __syncthreads();
    float thr = sThr;
    #pragma unroll
    for (int k = 0; k < 16; ++k){
        if (d2r[k] < thr){
            int p = atomicAdd(&cnt, 1);
            if (p < 256){ candD[p] = d2r[k]; candI[p] = tid + k * 256; }
        }
    }
    __syncthreads();
    int n = cnt < 256 ? cnt : 256;
    for (int c = tid; c < n; c += 256){
        float dv = candD[c]; int iv = candI[c];
        int rank = 0;
        for (int s = 0; s < n; ++s){
            float ds_ = candD[s]; int is_ = candI[s];
            rank += (ds_ < dv || (ds_ == dv && is_ < iv)) ? 1 : 0;
        }
        if (rank < M_NBR){
            nbr_idx[i * M_NBR + rank]  = iv;
            nbr_dist[i * M_NBR + rank] = sqrtf(dv);
        }
    }
}

// ---------------- 4 atoms/block, one wave per atom, W LDS-resident ----------------
// Block = 256 thr (4 independent waves); LDS = 48KB current-layer W (+1.5KB stash)
// -> 3 blocks/CU = 12 waves/CU. All MFMA B-operands from LDS (ds_read_b128);
// per-wave global traffic ~= gathers only. LN/products/reduce fully in-register.
__global__ __launch_bounds__(256) void k_atom(
        const float* __restrict__ atom0F, const u16* __restrict__ a0f,
        const int* __restrict__ nbr_idx, const float* __restrict__ nbr_dist,
        const u16* __restrict__ wpk,
        const float* __restrict__ b1, const float* __restrict__ g1, const float* __restrict__ be1,
        const float* __restrict__ b2, const float* __restrict__ g2, const float* __restrict__ be2,
        float* __restrict__ outF)
{
    __shared__ u16   wlds[24576];   // 48KB: current layer {S,N,G}
    __shared__ u16   sH[4][64];     // per-wave layer-1 out fp16 redistribution
    __shared__ float sO[4][64];     // per-wave output staging

    const int t = threadIdx.x;
    const int w = t >> 6, l = t & 63;
    const int lg = l >> 4, lr = l & 15;
    const int a = blockIdx.x * 4 + w;

    // ---- stage layer-1 W (issue first; overlaps prologue) ----
    {
        const float4* wsrc = (const float4*)wpk;
        #pragma unroll
        for (int it = 0; it < 12; ++it)
            ((float4*)wlds)[it * 256 + t] = wsrc[it * 256 + t];
    }

    // ---- prologue: per-wave independent loads ----
    const int slot = (lr < 12) ? lr : 11;
    const int nid  = nbr_idx[a * M_NBR + slot];
    const float dist = nbr_dist[a * M_NBR + slot];
    f16x8 nfr[2], saf[2];
    nfr[0] = *(const f16x8*)(a0f + nid * 64 + lg * 8);
    nfr[1] = *(const f16x8*)(a0f + nid * 64 + 32 + lg * 8);
    saf[0] = *(const f16x8*)(a0f + a * 64 + lg * 8);        // broadcast-A
    saf[1] = *(const f16x8*)(a0f + a * 64 + 32 + lg * 8);
    float resv[4];
    #pragma unroll
    for (int nt = 0; nt < 4; ++nt)
        resv[nt] = atom0F[(long)a * 64 + nt * 16 + lr];

    f16x8 ga[2];
    #pragma unroll
    for (int c = 0; c < 2; ++c)
        #pragma unroll
        for (int i = 0; i < 8; ++i){
            int k = c * 32 + lg * 8 + i;
            float dd = dist - (float)k * (8.0f / 63.0f);
            ga[c][i] = (_Float16)__expf(GAUSS_COEFF * dd * dd);
        }

    __syncthreads();   // B1: layer-1 W staged

    #pragma unroll 1
    for (int layer = 0; layer < 2; ++layer){
        const float* bb  = layer ? b2  : b1;
        const float* gg  = layer ? g2  : g1;
        const float* bee = layer ? be2 : be1;

        // fused S+N+G MFMA, B from LDS
        f32x4 acc[8];
        #pragma unroll
        for (int nt = 0; nt < 8; ++nt) acc[nt] = 0.0f;
        #pragma unroll
        for (int c = 0; c < 2; ++c)
            #pragma unroll
            for (int nt = 0; nt < 8; ++nt){
                const f16x8 bS = *(const f16x8*)(&wlds[         ((c * 8 + nt) * 64 + l) * 8]);
                const f16x8 bN = *(const f16x8*)(&wlds[ 8192 + ((c * 8 + nt) * 64 + l) * 8]);
                const f16x8 bG = *(const f16x8*)(&wlds[16384 + ((c * 8 + nt) * 64 + l) * 8]);
                acc[nt] = __builtin_amdgcn_mfma_f32_16x16x32_f16(saf[c], bS, acc[nt], 0, 0, 0);
                acc[nt] = __builtin_amdgcn_mfma_f32_16x16x32_f16(nfr[c], bN, acc[nt], 0, 0, 0);
                acc[nt] = __builtin_amdgcn_mfma_f32_16x16x32_f16(ga[c],  bG, acc[nt], 0, 0, 0);
            }

        // z = acc + bias; LN per row (row = lg*4+rr; cols nt*16+lr)
        float s[4] = {0,0,0,0}, q[4] = {0,0,0,0};
        #pragma unroll
        for (int nt = 0; nt < 8; ++nt){
            float bv = bb[nt * 16 + lr];
            #pragma unroll
            for (int rr = 0; rr < 4; ++rr){
                float v = acc[nt][rr] + bv;
                acc[nt][rr] = v;
                s[rr] += v; q[rr] += v * v;
            }
        }
        #pragma unroll
        for (int rr = 0; rr < 4; ++rr){
            #pragma unroll
            for (int m = 1; m < 16; m <<= 1){
                s[rr] += __shfl_xor(s[rr], m);
                q[rr] += __shfl_xor(q[rr], m);
            }
        }
        // products + per-atom reduction, in registers
        float nsum[4];
        #pragma unroll
        for (int nt = 0; nt < 4; ++nt){
            float gf = gg[nt * 16 + lr],      bef = bee[nt * 16 + lr];
            float gc = gg[64 + nt * 16 + lr], bec = bee[64 + nt * 16 + lr];
            float part = 0.0f;
            #pragma unroll
            for (int rr = 0; rr < 4; ++rr){
                float mean = s[rr] * (1.0f / 128.0f);
                float var  = q[rr] * (1.0f / 128.0f) - mean * mean;
                float inv  = rsqrtf(var + LN_EPS);
                float zf = (acc[nt][rr]     - mean) * inv * gf + bef;
                float zc = (acc[nt + 4][rr] - mean) * inv * gc + bec;
                part += sigmoidf_(zf) * softplusf_(zc);
            }
            if (lg == 3) part = 0.0f;          // padding rows 12-15
            part += __shfl_xor(part, 16);
            part += __shfl_xor(part, 32);
            nsum[nt] = part;
        }
        #pragma unroll
        for (int nt = 0; nt < 4; ++nt)
            resv[nt] = softplusf_(resv[nt] + nsum[nt]);

        if (layer == 0){
            // redistribute layer-1 out to A-fragments (intra-wave LDS, no barrier)
            if (lg == 0){
                #pragma unroll
                for (int nt = 0; nt < 4; ++nt)
                    sH[w][nt * 16 + lr] = f16bits((_Float16)resv[nt]);
            }
            saf[0] = *(const f16x8*)(&sH[w][lg * 8]);
            saf[1] = *(const f16x8*)(&sH[w][32 + lg * 8]);
            __syncthreads();   // B2: all layer-1 wlds reads done
            {
                const float4* wsrc2 = (const float4*)(wpk + 3 * 8192);
                #pragma unroll
                for (int it = 0; it < 12; ++it)
                    ((float4*)wlds)[it * 256 + t] = wsrc2[it * 256 + t];
            }
            __syncthreads();   // B3: layer-2 W staged
        } else {
            if (lg == 0){
                #pragma unroll
                for (int nt = 0; nt < 4; ++nt)
                    sO[w][nt * 16 + lr] = resv[nt];
            }
            outF[(long)a * 64 + l] = sO[w][l];
        }
    }
}

// ---------------- pooling: deterministic two-stage tree ----------------
__global__ __launch_bounds__(256) void k_partial(const float* __restrict__ atom,
        const float* __restrict__ occ, float* __restrict__ partials){
    int b = blockIdx.x, tid = threadIdx.x;
    int f = tid & 63, sub = tid >> 6;
    __shared__ float sAcc[256];
    float acc = 0.0f;
    for (int it = 0; it < 16; ++it){
        int a = b * 64 + sub + it * 4;
        float p = sigmoidf_(occ[a]);
        acc += atom[(long)a * FEA + f] * p;
    }
    sAcc[tid] = acc;
    __syncthreads();
    if (tid < 64){
        float s = sAcc[f] + sAcc[64 + f] + sAcc[128 + f] + sAcc[192 + f];
        partials[b * 65 + f] = s;
        float po = sigmoidf_(occ[b * 64 + f]);
        #pragma unroll
        for (int off = 32; off; off >>= 1) po += __shfl_down(po, off);
        if (f == 0) partials[b * 65 + 64] = po;
    }
}

__global__ __launch_bounds__(64) void k_final(const float* __restrict__ partials,
        const float* __restrict__ fc_w, const float* __restrict__ fc_b,
        float* __restrict__ out){
    int f = threadIdx.x;
    float num = 0.0f;
    for (int p = 0; p < 64; ++p) num += partials[p * 65 + f];
    float occs = partials[f * 65 + 64];
    #pragma unroll
    for (int off = 32; off; off >>= 1) occs += __shfl_down(occs, off);
    occs = __shfl(occs, 0);
    float gf = num / (occs + 1e-6f);
    float v = gf * fc_w[f];
    #pragma unroll
    for (int off = 32; off; off >>= 1) v += __shfl_down(v, off);
    if (f == 0) out[0] = v + fc_b[0];
}

extern "C" void kernel_launch(void* const* d_in, const int* in_sizes, int n_in,
                              void* d_out, int out_size, void* d_ws, size_t ws_size,
                              hipStream_t stream) {
    const float* lat    = (const float*)d_in[0];
    const float* fracs  = (const float*)d_in[1];
    const float* slog   = (const float*)d_in[2];
    const float* occ    = (const float*)d_in[3];
    const float* emb_w  = (const float*)d_in[4];
    const float* emb_b  = (const float*)d_in[5];
    const float* w1     = (const float*)d_in[6];
    const float* b1     = (const float*)d_in[7];
    const float* g1     = (const float*)d_in[8];
    const float* be1    = (const float*)d_in[9];
    const float* w2     = (const float*)d_in[10];
    const float* b2     = (const float*)d_in[11];
    const float* g2     = (const float*)d_in[12];
    const float* be2    = (const float*)d_in[13];
    const float* fc_w   = (const float*)d_in[14];
    const float* fc_b   = (const float*)d_in[15];
    float* out = (float*)d_out;

    char* ws = (char*)d_ws;
    auto alloc = [&](size_t bytes) -> void* {
        void* p = (void*)ws;
        ws += (bytes + 255) & ~(size_t)255;
        return p;
    };
    int*   nbr_idx  = (int*)  alloc((size_t)N_ATOMS * M_NBR * 4);
    float* nbr_dist = (float*)alloc((size_t)N_ATOMS * M_NBR * 4);
    float* atom0    = (float*)alloc((size_t)N_ATOMS * FEA * 4);
    float* atom1    = (float*)alloc((size_t)N_ATOMS * FEA * 4);
    u16*   a0f      = (u16*)  alloc((size_t)N_ATOMS * FEA * 2);
    u16*   wpk      = (u16*)  alloc((size_t)6 * 8192 * 2);
    float* fxa      = (float*)alloc((size_t)N_ATOMS * 4);
    float* fya      = (float*)alloc((size_t)N_ATOMS * 4);
    float* fza      = (float*)alloc((size_t)N_ATOMS * 4);
    float* partials = (float*)alloc((size_t)64 * 65 * 4);

    k_setup  <<<208 + N_ATOMS / 4, 256, 0, stream>>>(fracs, w1, w2, slog, emb_w, emb_b,
                fxa, fya, fza, wpk, atom0, a0f);
    k_topk   <<<N_ATOMS, 256, 0, stream>>>(fxa, fya, fza, lat, nbr_idx, nbr_dist);
    k_atom   <<<N_ATOMS / 4, 256, 0, stream>>>(atom0, a0f, nbr_idx, nbr_dist,
                wpk, b1, g1, be1, b2, g2, be2, atom1);
    k_partial<<<64, 256, 0, stream>>>(atom1, occ, partials);
    k_final  <<<1, 64, 0, stream>>>(partials, fc_w, fc_b, out);
}